// Round 7
// baseline (150.415 us; speedup 1.0000x reference)
//
#include <hip/hip_runtime.h>
#include <cstdint>
#include <cstddef>

// Problem constants (F, H, D, A, B) = (500, 2000, 64, 64, 4096)
#define F_N 500
#define H_N 2000
#define JN  2500   // F + H
#define D_N 64
#define A_N 64
#define B_N 4096

#define SPLIT  2         // blocks per attention row i (partial buffers, no atomics)
#define JCHUNK 1250      // JN / SPLIT

// ---------------------------------------------------------------------------
// Kernel 1 (fused pre+attn): 1000 blocks, block b: i = b/2, j-half b&1.
// k_pre is ELIMINATED — pre_f / pre_w are recomputed in-block:
//   - pf[a=lane]: 64 FMA once per block (W1 coalesced-read, L1-hit).
//   - scores wave-per-j: W2 column cached in 64 VGPRs (one coalesced load
//     per lane at start; re-reading W2 from L1 per-j would be ~2GB of L1
//     traffic), full[j] via uniform float4 broadcasts, 64 FMA per lane,
//     tanh, shfl_xor reduce for sum_a Wu[a]*tanh(...).
// Redundant FLOPs ~1 GFLOP (~10 us VALU) buy back k_pre's body AND a ~10 us
// dispatch boundary. No barriers/atomics (R3 lesson). Partials to disjoint
// csum[sub][i][d]/esum[sub][i] slots with plain stores.
// __launch_bounds__(256,4): cap VGPR at 128 (w2c[64]+~40 live) -> 4 blk/CU.
// ---------------------------------------------------------------------------
__global__ __launch_bounds__(256, 4) void k_attn_fused(
    const float* __restrict__ feat, const float* __restrict__ hid,
    const float* __restrict__ Ww,   const float* __restrict__ bw,
    const float* __restrict__ Wu,   const void* __restrict__ mask,
    float* __restrict__ csum, float* __restrict__ esum)
{
    const int tid  = threadIdx.x;
    const int lane = tid & 63;
    const int wave = tid >> 6;
    const int i    = blockIdx.x >> 1;          // 0..499
    const int sub  = blockIdx.x & 1;           // 0..1
    const int jbase = sub * JCHUNK;

    __shared__ int   list[JCHUNK];
    __shared__ float earr[JCHUNK];
    __shared__ float s_ctx[4][64];
    __shared__ float s_ss[4];
    __shared__ int   nact;

    if (tid == 0) nact = 0;

    // --- 0a: per-lane constants + W2 column into registers (STATIC idx!) ---
    const float wu = Wu[lane];
    float w2c[64];                             // W2[d][lane], d = 0..63
    #pragma unroll
    for (int d = 0; d < D_N; ++d)
        w2c[d] = Ww[(size_t)(D_N + d) * A_N + lane];   // W2 = Ww[64:128]

    // --- 0b: pf[a=lane] = bw[a] + feat[i,:] @ W1[:,a]  (all waves redundant)
    float pf = bw[lane];
    {
        const float* fr = feat + (size_t)i * D_N;       // block-uniform
        #pragma unroll
        for (int d = 0; d < D_N; ++d)
            pf = fmaf(fr[d], Ww[(size_t)d * A_N + lane], pf);
    }
    __syncthreads();                           // nact=0 visible

    // --- runtime mask-dtype detection: bool bytes vs int32 -----------------
    const uint32_t* mw = (const uint32_t*)mask;
    const uint32_t probe = mw[lane] | mw[64 + lane] | mw[128 + lane] | mw[192 + lane];
    const bool byteMode = (__ballot(probe > 1u) != 0ull);

    const uint8_t*  mb = (const uint8_t*)mask + (size_t)i * JN + jbase;
    const uint32_t* mi = (const uint32_t*)mask + (size_t)i * JN + jbase;

    // --- A: compaction over this block's 1250 j's (5 uniform passes) --------
    for (int t = tid; t < 1280; t += 256) {
        uint32_t m = 0;
        if (t < JCHUNK) m = byteMode ? (uint32_t)mb[t] : mi[t];
        const unsigned long long act = __ballot(m != 0);
        const int cnt = __popcll(act);
        int base = 0;
        if (lane == 0 && cnt) base = atomicAdd(&nact, cnt);
        base = __shfl(base, 0, 64);
        if (m) {
            const int rank = __popcll(act & ((1ull << lane) - 1ull));
            list[base + rank] = jbase + t;     // store GLOBAL j
        }
    }
    __syncthreads();
    const int n = nact;                        // ~125 active

    // --- B: scores, wave-per-j. lane = a. x = pf + full[j,:] @ W2[:,a] ------
    float ss_w = 0.0f;
    for (int pos = wave; pos < n; pos += 4) {
        const int j = __builtin_amdgcn_readfirstlane(list[pos]);  // wave-uniform
        const float* row = (j < F_N) ? (feat + (size_t)j * D_N)
                                     : (hid + (size_t)(j - F_N) * D_N);
        const float4* r4 = (const float4*)row;           // uniform b128 broadcast
        float x0 = pf, x1 = 0.0f;                        // 2 partials: shorter chain
        #pragma unroll
        for (int q = 0; q < 16; q += 2) {
            const float4 va = r4[q];
            const float4 vb = r4[q + 1];
            x0 = fmaf(va.x, w2c[4 * q + 0], x0);
            x0 = fmaf(va.y, w2c[4 * q + 1], x0);
            x0 = fmaf(va.z, w2c[4 * q + 2], x0);
            x0 = fmaf(va.w, w2c[4 * q + 3], x0);
            x1 = fmaf(vb.x, w2c[4 * q + 4], x1);
            x1 = fmaf(vb.y, w2c[4 * q + 5], x1);
            x1 = fmaf(vb.z, w2c[4 * q + 6], x1);
            x1 = fmaf(vb.w, w2c[4 * q + 7], x1);
        }
        const float x = x0 + x1;
        // tanh(x) = 1 - 2/(exp(2x)+1); v_rcp_f32 is plenty accurate here
        const float t = fmaf(-2.0f, __builtin_amdgcn_rcpf(__expf(2.0f * x) + 1.0f), 1.0f);
        float m = wu * t;                                // Wu[a] * tanh(.)
        #pragma unroll
        for (int off = 1; off < 64; off <<= 1) m += __shfl_xor(m, off, 64);
        const float e = __expf(m);                       // all lanes hold e
        if (lane == 0) earr[pos] = e;
        ss_w += e;                                       // lane-redundant
    }
    if (lane == 0) s_ss[wave] = ss_w;
    __syncthreads();

    // --- C: partial context accumulation (lane = d), 4x unrolled ------------
    float cacc = 0.0f;
    int idx = wave;                                      // stride 4 per wave
    for (; idx + 12 < n; idx += 16) {
        const float e0 = earr[idx];      const int j0 = list[idx];
        const float e1 = earr[idx + 4];  const int j1 = list[idx + 4];
        const float e2 = earr[idx + 8];  const int j2 = list[idx + 8];
        const float e3 = earr[idx + 12]; const int j3 = list[idx + 12];
        const float* r0 = (j0 < F_N) ? (feat + (size_t)j0 * D_N) : (hid + (size_t)(j0 - F_N) * D_N);
        const float* r1 = (j1 < F_N) ? (feat + (size_t)j1 * D_N) : (hid + (size_t)(j1 - F_N) * D_N);
        const float* r2 = (j2 < F_N) ? (feat + (size_t)j2 * D_N) : (hid + (size_t)(j2 - F_N) * D_N);
        const float* r3 = (j3 < F_N) ? (feat + (size_t)j3 * D_N) : (hid + (size_t)(j3 - F_N) * D_N);
        const float v0 = r0[lane];
        const float v1 = r1[lane];
        const float v2 = r2[lane];
        const float v3 = r3[lane];
        cacc = fmaf(e0, v0, cacc);
        cacc = fmaf(e1, v1, cacc);
        cacc = fmaf(e2, v2, cacc);
        cacc = fmaf(e3, v3, cacc);
    }
    for (; idx < n; idx += 4) {
        const float e = earr[idx];
        const int   j = list[idx];
        const float* row = (j < F_N) ? (feat + (size_t)j * D_N)
                                     : (hid + (size_t)(j - F_N) * D_N);
        cacc = fmaf(e, row[lane], cacc);
    }
    s_ctx[wave][lane] = cacc;
    __syncthreads();

    if (wave == 0) {
        const float c4 = s_ctx[0][lane] + s_ctx[1][lane] + s_ctx[2][lane] + s_ctx[3][lane];
        const float ss = s_ss[0] + s_ss[1] + s_ss[2] + s_ss[3];
        // disjoint partial slots: plain stores, no atomics, no zero-init
        csum[((size_t)sub * F_N + i) * D_N + lane] = c4;
        if (lane == 0) esum[sub * F_N + i] = ss;
    }
}

// ---------------------------------------------------------------------------
// Kernel 2: out = values (4096x500) @ ctx, where ctx[i][d] =
// (csum[0][i][d]+csum[1][i][d]) / guard(esum[0][i]+esum[1][i]).
// 512 blocks x 256 thr, 8 rows/block (2 rows/wave). Partial summation +
// normalization (incl. ssum==0 -> 1 guard) folded into the LDS staging;
// register-prefetch of chunk c+1 overlaps compute. values rows read as
// wave-uniform s_loads (readfirstlane'd row); ctx reads per-lane b32.
// ---------------------------------------------------------------------------
__global__ __launch_bounds__(256) void k_out(
    const float* __restrict__ values, const float* __restrict__ csum,
    const float* __restrict__ esum,   float* __restrict__ out)
{
    const int tid  = threadIdx.x;
    const int lane = tid & 63;
    const int wave = tid >> 6;
    int r0 = blockIdx.x * 8 + wave * 2;          // wave's first row
    r0 = __builtin_amdgcn_readfirstlane(r0);     // force scalar addressing

    __shared__ float ctx_l[100 * 64];            // 25.6 KB

    float4 cbuf0[7], cbuf1[7];                   // two partial ctx chunks
    float  ebuf[7];                              // summed esum per slot

    float acc0 = 0.0f, acc1 = 0.0f;

    // ---- prefetch chunk 0 (lane-coalesced) ----
    {
        const float4* cp0 = (const float4*)csum;                       // sub 0
        const float4* cp1 = (const float4*)(csum + (size_t)F_N * D_N); // sub 1
        #pragma unroll
        for (int q = 0; q < 7; ++q) {
            const int t = tid + q * 256;
            if (t < 1600) {
                cbuf0[q] = cp0[t];
                cbuf1[q] = cp1[t];
                ebuf[q]  = esum[t >> 4] + esum[F_N + (t >> 4)];
            }
        }
    }

    for (int chunk = 0; chunk < 5; ++chunk) {
        __syncthreads();                         // LDS free (prev compute done)
        // ---- registers -> LDS: sum partials + normalize ----
        {
            float4* cl = (float4*)ctx_l;
            #pragma unroll
            for (int q = 0; q < 7; ++q) {
                const int t = tid + q * 256;
                if (t < 1600) {
                    const float e   = ebuf[q];
                    const float inv = (e == 0.0f) ? 1.0f : __builtin_amdgcn_rcpf(e);
                    float4 c;
                    c.x = (cbuf0[q].x + cbuf1[q].x) * inv;
                    c.y = (cbuf0[q].y + cbuf1[q].y) * inv;
                    c.z = (cbuf0[q].z + cbuf1[q].z) * inv;
                    c.w = (cbuf0[q].w + cbuf1[q].w) * inv;
                    cl[t] = c;
                }
            }
        }
        __syncthreads();

        // ---- issue prefetch of chunk+1 (loads fly during compute) ----
        if (chunk < 4) {
            const int k0n = (chunk + 1) * 100;
            const float4* cp0 = (const float4*)(csum + (size_t)k0n * 64);
            const float4* cp1 = (const float4*)(csum + (size_t)(F_N + k0n) * 64);
            #pragma unroll
            for (int q = 0; q < 7; ++q) {
                const int t = tid + q * 256;
                if (t < 1600) {
                    cbuf0[q] = cp0[t];
                    cbuf1[q] = cp1[t];
                    ebuf[q]  = esum[k0n + (t >> 4)] + esum[F_N + k0n + (t >> 4)];
                }
            }
        }

        // ---- compute current chunk: ctx from LDS, values via s_loads ----
        const int k0 = chunk * 100;
        const float* v0 = values + (size_t)(r0 + 0) * 500 + k0;  // scalar ptr
        const float* v1 = values + (size_t)(r0 + 1) * 500 + k0;
        #pragma unroll 10
        for (int k = 0; k < 100; k += 4) {
            const float c0 = ctx_l[(k + 0) * 64 + lane];
            const float c1 = ctx_l[(k + 1) * 64 + lane];
            const float c2 = ctx_l[(k + 2) * 64 + lane];
            const float c3 = ctx_l[(k + 3) * 64 + lane];
            acc0 = fmaf(v0[k + 0], c0, acc0); acc0 = fmaf(v0[k + 1], c1, acc0);
            acc0 = fmaf(v0[k + 2], c2, acc0); acc0 = fmaf(v0[k + 3], c3, acc0);
            acc1 = fmaf(v1[k + 0], c0, acc1); acc1 = fmaf(v1[k + 1], c1, acc1);
            acc1 = fmaf(v1[k + 2], c2, acc1); acc1 = fmaf(v1[k + 3], c3, acc1);
        }
    }

    out[(size_t)(r0 + 0) * 64 + lane] = acc0;    // coalesced 256 B per wave
    out[(size_t)(r0 + 1) * 64 + lane] = acc1;
}

// ---------------------------------------------------------------------------
extern "C" void kernel_launch(void* const* d_in, const int* in_sizes, int n_in,
                              void* d_out, int out_size, void* d_ws, size_t ws_size,
                              hipStream_t stream)
{
    const float* values = (const float*)d_in[0];   // (4096, 500)
    const float* feat   = (const float*)d_in[1];   // (500, 64)
    const float* hid    = (const float*)d_in[2];   // (2000, 64)
    const float* Ww     = (const float*)d_in[3];   // (128, 64)
    const float* bw     = (const float*)d_in[4];   // (64,)
    const float* Wu     = (const float*)d_in[5];   // (64, 1)
    const void*  mask   = d_in[6];                 // (500, 2500, 1) — dtype detected on device
    float* out = (float*)d_out;                    // (4096, 64)

    // Workspace layout (floats): csum[2*32000] | esum[2*500]
    float* wsf  = (float*)d_ws;
    float* csum = wsf;                   // 64000 floats (2 partial buffers)
    float* esum = wsf + 64000;           // 1000 floats  (2 partial buffers)

    k_attn_fused<<<1000, 256, 0, stream>>>(feat, hid, Ww, bw, Wu, mask, csum, esum);
    k_out       <<<512,  256, 0, stream>>>(values, csum, esum, out);
}

// Round 8
// 139.761 us; speedup vs baseline: 1.0762x; 1.0762x over previous
//
#include <hip/hip_runtime.h>
#include <cstdint>
#include <cstddef>

// Problem constants (F, H, D, A, B) = (500, 2000, 64, 64, 4096)
#define F_N 500
#define H_N 2000
#define JN  2500   // F + H
#define D_N 64
#define A_N 64
#define B_N 4096

#define SPLIT  2         // blocks per attention row i (partial buffers, no atomics)
#define JCHUNK 1250      // JN / SPLIT

// ---------------------------------------------------------------------------
// Kernel 1 (fused pre+attn): 1000 blocks, block b: i = b/2, j-half b&1.
// k_pre is eliminated; pre-activations are recomputed in-block.
// R7 lesson: per-lane w2c[64] register cache SPILLED (VGPR=64, 18 MB scratch
// writes). Fix: W2 lives in LDS (16 KB, deterministic). Phase B is wave-per-j:
//   x[a=lane] = pf[lane] + sum_d full[j][d] * w2_lds[d*64+lane]
// full[j] via wave-uniform s_load_dwordx4 (readfirstlane'd j); w2 reads are
// conflict-free (consecutive words across lanes, ds_read2-foldable); then
// tanh, Wu[a]*t, 6-step shfl_xor reduce, exp. No barriers/atomics between
// blocks. Partials to disjoint csum[sub][i][d]/esum[sub][i] slots.
// LDS 27.4 KB -> 5 blocks/CU; launch_bounds(256,4) -> VGPR<=128, no arrays.
// ---------------------------------------------------------------------------
__global__ __launch_bounds__(256, 4) void k_attn_fused(
    const float* __restrict__ feat, const float* __restrict__ hid,
    const float* __restrict__ Ww,   const float* __restrict__ bw,
    const float* __restrict__ Wu,   const void* __restrict__ mask,
    float* __restrict__ csum, float* __restrict__ esum)
{
    const int tid  = threadIdx.x;
    const int lane = tid & 63;
    const int wave = tid >> 6;
    const int i    = blockIdx.x >> 1;          // 0..499
    const int sub  = blockIdx.x & 1;           // 0..1
    const int jbase = sub * JCHUNK;

    __shared__ float w2[D_N * A_N];            // 16 KB: W2[d][a], d-major
    __shared__ int   list[JCHUNK];             // 5 KB
    __shared__ float earr[JCHUNK];             // 5 KB
    __shared__ float s_ctx[4][64];             // 1 KB
    __shared__ float s_ss[4];
    __shared__ int   nact;

    if (tid == 0) nact = 0;

    // --- 0a: stage W2 into LDS (contiguous rows 64..127 of Ww) -------------
    {
        const float4* src = (const float4*)(Ww + (size_t)D_N * A_N);
        float4*       dst = (float4*)w2;
        #pragma unroll
        for (int q = 0; q < 4; ++q) dst[tid + q * 256] = src[tid + q * 256];
    }

    // --- 0b: pf[a=lane] = bw[a] + feat[i,:] @ W1[:,a]  (all waves redundant)
    const float wu = Wu[lane];
    float pf = bw[lane];
    {
        const float* fr = feat + (size_t)i * D_N;       // block-uniform
        #pragma unroll
        for (int d = 0; d < D_N; ++d)
            pf = fmaf(fr[d], Ww[(size_t)d * A_N + lane], pf);
    }
    __syncthreads();                           // nact=0 + w2 staged visible

    // --- runtime mask-dtype detection: bool bytes vs int32 -----------------
    const uint32_t* mw = (const uint32_t*)mask;
    const uint32_t probe = mw[lane] | mw[64 + lane] | mw[128 + lane] | mw[192 + lane];
    const bool byteMode = (__ballot(probe > 1u) != 0ull);

    const uint8_t*  mb = (const uint8_t*)mask + (size_t)i * JN + jbase;
    const uint32_t* mi = (const uint32_t*)mask + (size_t)i * JN + jbase;

    // --- A: compaction over this block's 1250 j's (5 uniform passes) --------
    for (int t = tid; t < 1280; t += 256) {
        uint32_t m = 0;
        if (t < JCHUNK) m = byteMode ? (uint32_t)mb[t] : mi[t];
        const unsigned long long act = __ballot(m != 0);
        const int cnt = __popcll(act);
        int base = 0;
        if (lane == 0 && cnt) base = atomicAdd(&nact, cnt);
        base = __shfl(base, 0, 64);
        if (m) {
            const int rank = __popcll(act & ((1ull << lane) - 1ull));
            list[base + rank] = jbase + t;     // store GLOBAL j
        }
    }
    __syncthreads();
    const int n = nact;                        // ~125 active

    // --- B: scores, wave-per-j. lane = a. x = pf + full[j,:] @ W2[:,a] ------
    float ss_w = 0.0f;
    for (int pos = wave; pos < n; pos += 4) {
        const int j = __builtin_amdgcn_readfirstlane(list[pos]);  // wave-uniform
        const float* row = (j < F_N) ? (feat + (size_t)j * D_N)
                                     : (hid + (size_t)(j - F_N) * D_N);
        float x0 = pf, x1 = 0.0f;              // 2 partials: shorter dep chain
        #pragma unroll
        for (int d = 0; d < D_N; d += 4) {
            const float4 rv = *(const float4*)(row + d);   // s_load_dwordx4
            x0 = fmaf(rv.x, w2[(d + 0) * A_N + lane], x0); // conflict-free LDS
            x1 = fmaf(rv.y, w2[(d + 1) * A_N + lane], x1);
            x0 = fmaf(rv.z, w2[(d + 2) * A_N + lane], x0);
            x1 = fmaf(rv.w, w2[(d + 3) * A_N + lane], x1);
        }
        const float x = x0 + x1;
        // tanh(x) = 1 - 2/(exp(2x)+1); v_rcp_f32 is plenty accurate here
        const float t = fmaf(-2.0f, __builtin_amdgcn_rcpf(__expf(2.0f * x) + 1.0f), 1.0f);
        float m = wu * t;                      // Wu[a] * tanh(.)
        #pragma unroll
        for (int off = 1; off < 64; off <<= 1) m += __shfl_xor(m, off, 64);
        const float e = __expf(m);             // all lanes hold e
        if (lane == 0) earr[pos] = e;
        ss_w += e;                             // lane-redundant accumulate
    }
    if (lane == 0) s_ss[wave] = ss_w;
    __syncthreads();

    // --- C: partial context accumulation (lane = d), 4x unrolled ------------
    float cacc = 0.0f;
    int idx = wave;                            // stride 4 per wave
    for (; idx + 12 < n; idx += 16) {
        const float e0 = earr[idx];      const int j0 = list[idx];
        const float e1 = earr[idx + 4];  const int j1 = list[idx + 4];
        const float e2 = earr[idx + 8];  const int j2 = list[idx + 8];
        const float e3 = earr[idx + 12]; const int j3 = list[idx + 12];
        const float* r0 = (j0 < F_N) ? (feat + (size_t)j0 * D_N) : (hid + (size_t)(j0 - F_N) * D_N);
        const float* r1 = (j1 < F_N) ? (feat + (size_t)j1 * D_N) : (hid + (size_t)(j1 - F_N) * D_N);
        const float* r2 = (j2 < F_N) ? (feat + (size_t)j2 * D_N) : (hid + (size_t)(j2 - F_N) * D_N);
        const float* r3 = (j3 < F_N) ? (feat + (size_t)j3 * D_N) : (hid + (size_t)(j3 - F_N) * D_N);
        const float v0 = r0[lane];
        const float v1 = r1[lane];
        const float v2 = r2[lane];
        const float v3 = r3[lane];
        cacc = fmaf(e0, v0, cacc);
        cacc = fmaf(e1, v1, cacc);
        cacc = fmaf(e2, v2, cacc);
        cacc = fmaf(e3, v3, cacc);
    }
    for (; idx < n; idx += 4) {
        const float e = earr[idx];
        const int   j = list[idx];
        const float* row = (j < F_N) ? (feat + (size_t)j * D_N)
                                     : (hid + (size_t)(j - F_N) * D_N);
        cacc = fmaf(e, row[lane], cacc);
    }
    s_ctx[wave][lane] = cacc;
    __syncthreads();

    if (wave == 0) {
        const float c4 = s_ctx[0][lane] + s_ctx[1][lane] + s_ctx[2][lane] + s_ctx[3][lane];
        const float ss = s_ss[0] + s_ss[1] + s_ss[2] + s_ss[3];
        // disjoint partial slots: plain stores, no atomics, no zero-init
        csum[((size_t)sub * F_N + i) * D_N + lane] = c4;
        if (lane == 0) esum[sub * F_N + i] = ss;
    }
}

// ---------------------------------------------------------------------------
// Kernel 2: out = values (4096x500) @ ctx, where ctx[i][d] =
// (csum[0][i][d]+csum[1][i][d]) / guard(esum[0][i]+esum[1][i]).
// 512 blocks x 256 thr, 8 rows/block (2 rows/wave). Partial summation +
// normalization (incl. ssum==0 -> 1 guard) folded into the LDS staging;
// register-prefetch of chunk c+1 overlaps compute. values rows read as
// wave-uniform s_loads (readfirstlane'd row); ctx reads per-lane b32.
// ---------------------------------------------------------------------------
__global__ __launch_bounds__(256) void k_out(
    const float* __restrict__ values, const float* __restrict__ csum,
    const float* __restrict__ esum,   float* __restrict__ out)
{
    const int tid  = threadIdx.x;
    const int lane = tid & 63;
    const int wave = tid >> 6;
    int r0 = blockIdx.x * 8 + wave * 2;          // wave's first row
    r0 = __builtin_amdgcn_readfirstlane(r0);     // force scalar addressing

    __shared__ float ctx_l[100 * 64];            // 25.6 KB

    float4 cbuf0[7], cbuf1[7];                   // two partial ctx chunks
    float  ebuf[7];                              // summed esum per slot

    float acc0 = 0.0f, acc1 = 0.0f;

    // ---- prefetch chunk 0 (lane-coalesced) ----
    {
        const float4* cp0 = (const float4*)csum;                       // sub 0
        const float4* cp1 = (const float4*)(csum + (size_t)F_N * D_N); // sub 1
        #pragma unroll
        for (int q = 0; q < 7; ++q) {
            const int t = tid + q * 256;
            if (t < 1600) {
                cbuf0[q] = cp0[t];
                cbuf1[q] = cp1[t];
                ebuf[q]  = esum[t >> 4] + esum[F_N + (t >> 4)];
            }
        }
    }

    for (int chunk = 0; chunk < 5; ++chunk) {
        __syncthreads();                         // LDS free (prev compute done)
        // ---- registers -> LDS: sum partials + normalize ----
        {
            float4* cl = (float4*)ctx_l;
            #pragma unroll
            for (int q = 0; q < 7; ++q) {
                const int t = tid + q * 256;
                if (t < 1600) {
                    const float e   = ebuf[q];
                    const float inv = (e == 0.0f) ? 1.0f : __builtin_amdgcn_rcpf(e);
                    float4 c;
                    c.x = (cbuf0[q].x + cbuf1[q].x) * inv;
                    c.y = (cbuf0[q].y + cbuf1[q].y) * inv;
                    c.z = (cbuf0[q].z + cbuf1[q].z) * inv;
                    c.w = (cbuf0[q].w + cbuf1[q].w) * inv;
                    cl[t] = c;
                }
            }
        }
        __syncthreads();

        // ---- issue prefetch of chunk+1 (loads fly during compute) ----
        if (chunk < 4) {
            const int k0n = (chunk + 1) * 100;
            const float4* cp0 = (const float4*)(csum + (size_t)k0n * 64);
            const float4* cp1 = (const float4*)(csum + (size_t)(F_N + k0n) * 64);
            #pragma unroll
            for (int q = 0; q < 7; ++q) {
                const int t = tid + q * 256;
                if (t < 1600) {
                    cbuf0[q] = cp0[t];
                    cbuf1[q] = cp1[t];
                    ebuf[q]  = esum[k0n + (t >> 4)] + esum[F_N + k0n + (t >> 4)];
                }
            }
        }

        // ---- compute current chunk: ctx from LDS, values via s_loads ----
        const int k0 = chunk * 100;
        const float* v0 = values + (size_t)(r0 + 0) * 500 + k0;  // scalar ptr
        const float* v1 = values + (size_t)(r0 + 1) * 500 + k0;
        #pragma unroll 10
        for (int k = 0; k < 100; k += 4) {
            const float c0 = ctx_l[(k + 0) * 64 + lane];
            const float c1 = ctx_l[(k + 1) * 64 + lane];
            const float c2 = ctx_l[(k + 2) * 64 + lane];
            const float c3 = ctx_l[(k + 3) * 64 + lane];
            acc0 = fmaf(v0[k + 0], c0, acc0); acc0 = fmaf(v0[k + 1], c1, acc0);
            acc0 = fmaf(v0[k + 2], c2, acc0); acc0 = fmaf(v0[k + 3], c3, acc0);
            acc1 = fmaf(v1[k + 0], c0, acc1); acc1 = fmaf(v1[k + 1], c1, acc1);
            acc1 = fmaf(v1[k + 2], c2, acc1); acc1 = fmaf(v1[k + 3], c3, acc1);
        }
    }

    out[(size_t)(r0 + 0) * 64 + lane] = acc0;    // coalesced 256 B per wave
    out[(size_t)(r0 + 1) * 64 + lane] = acc1;
}

// ---------------------------------------------------------------------------
extern "C" void kernel_launch(void* const* d_in, const int* in_sizes, int n_in,
                              void* d_out, int out_size, void* d_ws, size_t ws_size,
                              hipStream_t stream)
{
    const float* values = (const float*)d_in[0];   // (4096, 500)
    const float* feat   = (const float*)d_in[1];   // (500, 64)
    const float* hid    = (const float*)d_in[2];   // (2000, 64)
    const float* Ww     = (const float*)d_in[3];   // (128, 64)
    const float* bw     = (const float*)d_in[4];   // (64,)
    const float* Wu     = (const float*)d_in[5];   // (64, 1)
    const void*  mask   = d_in[6];                 // (500, 2500, 1) — dtype detected on device
    float* out = (float*)d_out;                    // (4096, 64)

    // Workspace layout (floats): csum[2*32000] | esum[2*500]
    float* wsf  = (float*)d_ws;
    float* csum = wsf;                   // 64000 floats (2 partial buffers)
    float* esum = wsf + 64000;           // 1000 floats  (2 partial buffers)

    k_attn_fused<<<1000, 256, 0, stream>>>(feat, hid, Ww, bw, Wu, mask, csum, esum);
    k_out       <<<512,  256, 0, stream>>>(values, csum, esum, out);
}